// Round 5
// baseline (259.649 us; speedup 1.0000x reference)
//
#include <hip/hip_runtime.h>
#include <stdint.h>

#define BATCH 8
#define NN 4096
#define CC 64
#define MASKV -1.0e30f
#define LOG2E 1.4426950408889634f

typedef _Float16 half8 __attribute__((ext_vector_type(8)));
typedef __fp16 fp16x2 __attribute__((ext_vector_type(2)));
typedef float f32x4 __attribute__((ext_vector_type(4)));

// ------------------------------------------------------------------
// Projection: q (fp16 hi+lo, pre-scaled by log2e), k (fp16), vT (fp16,
// [b][c][n]). Split-compensated fp16 MFMA -> only fp16 STORAGE
// rounding (2^-11) survives into the attention matmuls.
// ------------------------------------------------------------------
__global__ __launch_bounds__(256) void gat_proj(
    const float* __restrict__ X, const float* __restrict__ W0,
    const float* __restrict__ Wq, const float* __restrict__ Wk,
    _Float16* __restrict__ qh, _Float16* __restrict__ ql,
    _Float16* __restrict__ kb, _Float16* __restrict__ vt)
{
    __shared__ alignas(16) _Float16 WTh[3][64][72];   // [mat][c_out][c_in], +8 pad
    __shared__ alignas(16) _Float16 WTl[3][64][72];
    const int t = threadIdx.x;
    const float* Ws[3] = {W0, Wq, Wk};
    for (int e = t; e < 4096; e += 256) {
        int k = e >> 6, c = e & 63;
        #pragma unroll
        for (int m = 0; m < 3; ++m) {
            float w = Ws[m][e];
            _Float16 hi = (_Float16)w;
            WTh[m][c][k] = hi;
            WTl[m][c][k] = (_Float16)(w - (float)hi);
        }
    }
    __syncthreads();
    const int lane = t & 63, wv = t >> 6;
    const int cl = lane & 15, g = lane >> 4;
    {
        int tile = blockIdx.x * 4 + wv;               // 2048 tiles of 16 rows
        int gr = tile * 16;
        const float* xr = X + (size_t)(gr + cl) * CC;
        half8 xh[2], xl[2];
        #pragma unroll
        for (int kf = 0; kf < 2; ++kf) {
            f32x4 a0 = *(const f32x4*)(xr + g*8 + kf*32);
            f32x4 a1 = *(const f32x4*)(xr + g*8 + kf*32 + 4);
            half8 h, l;
            #pragma unroll
            for (int j = 0; j < 4; ++j) {
                _Float16 h0 = (_Float16)a0[j], h1 = (_Float16)a1[j];
                h[j]   = h0; l[j]   = (_Float16)(a0[j] - (float)h0);
                h[j+4] = h1; l[j+4] = (_Float16)(a1[j] - (float)h1);
            }
            xh[kf] = h; xl[kf] = l;
        }
        // q and k: D[row][c_out] = X * W
        #pragma unroll
        for (int mat = 1; mat <= 2; ++mat) {
            #pragma unroll
            for (int nt = 0; nt < 4; ++nt) {
                f32x4 acc = {0.f, 0.f, 0.f, 0.f};
                #pragma unroll
                for (int kf = 0; kf < 2; ++kf) {
                    half8 bh = *(const half8*)&WTh[mat][nt*16 + cl][g*8 + kf*32];
                    half8 bl = *(const half8*)&WTl[mat][nt*16 + cl][g*8 + kf*32];
                    acc = __builtin_amdgcn_mfma_f32_16x16x32_f16(xh[kf], bh, acc, 0, 0, 0);
                    acc = __builtin_amdgcn_mfma_f32_16x16x32_f16(xl[kf], bh, acc, 0, 0, 0);
                    acc = __builtin_amdgcn_mfma_f32_16x16x32_f16(xh[kf], bl, acc, 0, 0, 0);
                }
                #pragma unroll
                for (int i = 0; i < 4; ++i) {
                    size_t off = (size_t)(gr + 4*g + i) * CC + nt*16 + cl;
                    if (mat == 1) {
                        float qs = acc[i] * LOG2E;        // fold log2e for exp2 softmax
                        _Float16 hi = (_Float16)qs;
                        qh[off] = hi;
                        ql[off] = (_Float16)(qs - (float)hi);
                    } else {
                        kb[off] = (_Float16)acc[i];
                    }
                }
            }
        }
        // vT: D[c_out][row] = W^T * X^T -> [b][c][n] layout
        {
            int b = gr >> 12, n0 = gr & (NN - 1);
            #pragma unroll
            for (int mt = 0; mt < 4; ++mt) {
                f32x4 acc = {0.f, 0.f, 0.f, 0.f};
                #pragma unroll
                for (int kf = 0; kf < 2; ++kf) {
                    half8 ah = *(const half8*)&WTh[0][mt*16 + cl][g*8 + kf*32];
                    half8 al = *(const half8*)&WTl[0][mt*16 + cl][g*8 + kf*32];
                    acc = __builtin_amdgcn_mfma_f32_16x16x32_f16(ah, xh[kf], acc, 0, 0, 0);
                    acc = __builtin_amdgcn_mfma_f32_16x16x32_f16(al, xh[kf], acc, 0, 0, 0);
                    acc = __builtin_amdgcn_mfma_f32_16x16x32_f16(ah, xl[kf], acc, 0, 0, 0);
                }
                #pragma unroll
                for (int i = 0; i < 4; ++i) {
                    int co = mt*16 + 4*g + i;
                    vt[((size_t)b * CC + co) * NN + n0 + cl] = (_Float16)acc[i];
                }
            }
        }
    }
}

// ------------------------------------------------------------------
// Adjacency -> bitmask (forced diagonal). One block per row; each
// thread packs 16 keys (4x int4 loads) into one u16 store. Writes the
// same M buffer attn reads as u64 words (little-endian bit order ok).
// ------------------------------------------------------------------
__global__ __launch_bounds__(256) void gat_mask(const int* __restrict__ A,
                                                unsigned short* __restrict__ M16)
{
    const int row = blockIdx.x;
    const int w16 = threadIdx.x;
    const int4* ap = (const int4*)(A + (size_t)row * NN + w16 * 16);
    unsigned m = 0;
    #pragma unroll
    for (int j = 0; j < 4; ++j) {
        int4 a = ap[j];
        m |= (a.x != 0 ? 1u : 0u) << (4*j);
        m |= (a.y != 0 ? 1u : 0u) << (4*j + 1);
        m |= (a.z != 0 ? 1u : 0u) << (4*j + 2);
        m |= (a.w != 0 ? 1u : 0u) << (4*j + 3);
    }
    if (w16 == (row >> 4)) m |= 1u << (row & 15);
    M16[(size_t)row * 256 + w16] = (unsigned short)m;
}

// ------------------------------------------------------------------
// Flash attention, split-K x4: 1024 blocks (8b x 32qtile x 4sp) -> 4
// blocks/CU resident (36 KB LDS), 16 waves/CU. Single-buffered K/V
// chunk staging (stride 72), register prefetch of the next chunk
// hides global latency; cross-block overlap hides barrier drains.
// Partials (fp16 o, fp32 m/l) merged by gat_comb.
// ------------------------------------------------------------------
__global__ __launch_bounds__(256, 4) void gat_attn(
    const _Float16* __restrict__ qh, const _Float16* __restrict__ ql,
    const _Float16* __restrict__ kf16, const _Float16* __restrict__ vtb,
    const unsigned long long* __restrict__ M,
    _Float16* __restrict__ po, float2* __restrict__ pml)
{
    __shared__ alignas(16) _Float16 Kt[64][72];       // [key][c_in]
    __shared__ alignas(16) _Float16 Vt[64][72];       // [c_out][key]
    __shared__ alignas(16) _Float16 Ps[4][32][72];    // per-wave [qrow][key]
    const int t = threadIdx.x;
    const int lane = t & 63, wv = t >> 6;
    const int cl = lane & 15, g = lane >> 4;
    const int blk = blockIdx.x;        // 1024
    const int sp = blk & 3;            // key split
    const int qb = (blk >> 2) & 31;    // q tile
    const int b  = blk >> 7;           // batch
    const int Q0 = qb * 128 + wv * 32;
    const int c0 = sp * 16;            // first 64-key chunk of this split

    half8 qfh[2][2], qfl[2][2];
    #pragma unroll
    for (int qt = 0; qt < 2; ++qt) {
        const _Float16* qrh = qh + ((size_t)b * NN + Q0 + qt*16 + cl) * CC;
        const _Float16* qrl = ql + ((size_t)b * NN + Q0 + qt*16 + cl) * CC;
        qfh[qt][0] = *(const half8*)(qrh + g*8);
        qfh[qt][1] = *(const half8*)(qrh + g*8 + 32);
        qfl[qt][0] = *(const half8*)(qrl + g*8);
        qfl[qt][1] = *(const half8*)(qrl + g*8 + 32);
    }
    const _Float16* kg = kf16 + (size_t)b * NN * CC;
    const _Float16* vg = vtb + (size_t)b * CC * NN;

    f32x4 o[2][4] = {};
    float m_run[2] = {MASKV, MASKV}, l_run[2] = {0.f, 0.f};

    uint4 pk0, pk1, pv0, pv1;
    unsigned long long pmA, pmB;
    auto loadchunk = [&](int kc) {                    // kc = global chunk id
        const uint4* ks = (const uint4*)(kg + (size_t)kc * 64 * CC);
        pk0 = ks[t];
        pk1 = ks[t + 256];
        const _Float16* vs = vg + kc * 64;
        pv0 = *(const uint4*)(vs + (size_t)(t >> 3) * NN + (t & 7) * 8);
        pv1 = *(const uint4*)(vs + (size_t)((t >> 3) + 32) * NN + (t & 7) * 8);
        pmA = M[(size_t)(Q0 + cl) * 64 + kc];
        pmB = M[(size_t)(Q0 + 16 + cl) * 64 + kc];
    };
    loadchunk(c0);

    for (int kc = 0; kc < 16; ++kc) {
        __syncthreads();                 // previous tile's consumers done
        *(uint4*)&Kt[t >> 3][(t & 7) * 8] = pk0;
        *(uint4*)&Kt[(t >> 3) + 32][(t & 7) * 8] = pk1;
        *(uint4*)&Vt[t >> 3][(t & 7) * 8] = pv0;
        *(uint4*)&Vt[(t >> 3) + 32][(t & 7) * 8] = pv1;
        const unsigned long long cmA = pmA, cmB = pmB;
        __syncthreads();                 // tile ready
        if (kc < 15) loadchunk(c0 + kc + 1);   // overlap with compute

        // S^T tiles: D[key][qrow]; q hi/lo fp16 (K frag reused)
        f32x4 sc[2][4] = {};
        #pragma unroll
        for (int kt = 0; kt < 4; ++kt) {
            #pragma unroll
            for (int kf = 0; kf < 2; ++kf) {
                half8 ka = *(const half8*)&Kt[kt*16 + cl][g*8 + kf*32];
                sc[0][kt] = __builtin_amdgcn_mfma_f32_16x16x32_f16(ka, qfh[0][kf], sc[0][kt], 0, 0, 0);
                sc[0][kt] = __builtin_amdgcn_mfma_f32_16x16x32_f16(ka, qfl[0][kf], sc[0][kt], 0, 0, 0);
                sc[1][kt] = __builtin_amdgcn_mfma_f32_16x16x32_f16(ka, qfh[1][kf], sc[1][kt], 0, 0, 0);
                sc[1][kt] = __builtin_amdgcn_mfma_f32_16x16x32_f16(ka, qfl[1][kf], sc[1][kt], 0, 0, 0);
            }
        }

        // softmax (exp2 domain); lane owns q-row qt*16+cl
        #pragma unroll
        for (int qt = 0; qt < 2; ++qt) {
            const unsigned long long cm = qt ? cmB : cmA;
            const unsigned mwx = (unsigned)cm, mwy = (unsigned)(cm >> 32);
            float sv[16];
            float mx = MASKV;
            #pragma unroll
            for (int kt = 0; kt < 4; ++kt) {
                unsigned wmw = (kt < 2) ? mwx : mwy;
                #pragma unroll
                for (int i = 0; i < 4; ++i) {
                    float x = sc[qt][kt][i];
                    x = fmaxf(x, 0.01f * x);              // leaky_relu
                    int bit = ((kt & 1) * 16) + 4*g + i;
                    x = ((wmw >> bit) & 1u) ? x : MASKV;
                    sv[kt*4 + i] = x;
                    mx = fmaxf(mx, x);
                }
            }
            mx = fmaxf(mx, __shfl_xor(mx, 16));
            mx = fmaxf(mx, __shfl_xor(mx, 32));
            if (__any(mx > m_run[qt])) {                   // wave-uniform skip
                float nm = fmaxf(m_run[qt], mx);
                float alpha = __builtin_amdgcn_exp2f(m_run[qt] - nm);
                m_run[qt] = nm;
                l_run[qt] *= alpha;
                #pragma unroll
                for (int ct = 0; ct < 4; ++ct) o[qt][ct] *= alpha;
            }
            float lsum = 0.f;
            float p[16];
            #pragma unroll
            for (int j = 0; j < 16; ++j) {
                p[j] = __builtin_amdgcn_exp2f(sv[j] - m_run[qt]);  // masked -> 0
                lsum += p[j];
            }
            l_run[qt] += lsum;
            #pragma unroll
            for (int kt = 0; kt < 4; ++kt) {
                union { fp16x2 h; unsigned u; } p0u, p1u;
                p0u.h = __builtin_amdgcn_cvt_pkrtz(p[kt*4+0], p[kt*4+1]);
                p1u.h = __builtin_amdgcn_cvt_pkrtz(p[kt*4+2], p[kt*4+3]);
                uint2 pw = {p0u.u, p1u.u};
                *(uint2*)&Ps[wv][qt*16 + cl][kt*16 + 4*g] = pw;
            }
        }
        __builtin_amdgcn_wave_barrier();   // same-wave DS in-order; fence scheduler

        half8 pf[2][2];
        #pragma unroll
        for (int qt = 0; qt < 2; ++qt) {
            pf[qt][0] = *(const half8*)&Ps[wv][qt*16 + cl][g*8];
            pf[qt][1] = *(const half8*)&Ps[wv][qt*16 + cl][g*8 + 32];
        }
        // O^T += V^T * P^T
        #pragma unroll
        for (int ct = 0; ct < 4; ++ct) {
            half8 vf0 = *(const half8*)&Vt[ct*16 + cl][g*8];
            half8 vf1 = *(const half8*)&Vt[ct*16 + cl][g*8 + 32];
            #pragma unroll
            for (int qt = 0; qt < 2; ++qt) {
                o[qt][ct] = __builtin_amdgcn_mfma_f32_16x16x32_f16(vf0, pf[qt][0], o[qt][ct], 0, 0, 0);
                o[qt][ct] = __builtin_amdgcn_mfma_f32_16x16x32_f16(vf1, pf[qt][1], o[qt][ct], 0, 0, 0);
            }
        }
    }

    // epilogue: store UNNORMALIZED fp16 partial o + (m, l) for combine
    #pragma unroll
    for (int qt = 0; qt < 2; ++qt) {
        float lt = l_run[qt];
        lt += __shfl_xor(lt, 16);
        lt += __shfl_xor(lt, 32);
        size_t base = (size_t)sp * (BATCH * NN) + (size_t)b * NN + Q0 + qt*16 + cl;
        _Float16* orow = po + base * 64;
        #pragma unroll
        for (int ct = 0; ct < 4; ++ct) {
            union { fp16x2 h; unsigned u; } o0u, o1u;
            o0u.h = __builtin_amdgcn_cvt_pkrtz(o[qt][ct][0], o[qt][ct][1]);
            o1u.h = __builtin_amdgcn_cvt_pkrtz(o[qt][ct][2], o[qt][ct][3]);
            uint2 ow = {o0u.u, o1u.u};
            *(uint2*)(orow + ct*16 + 4*g) = ow;
        }
        if (g == 0) pml[base] = make_float2(m_run[qt], lt);
    }
}

// ------------------------------------------------------------------
// Combine the 4 split-K partials: out = sum_s w_s*o_s / sum_s w_s*l_s,
// w_s = exp2(m_s - max_s m_s). Fully-masked splits get w=0.
// ------------------------------------------------------------------
__global__ __launch_bounds__(256) void gat_comb(
    const _Float16* __restrict__ po, const float2* __restrict__ pml,
    float* __restrict__ out)
{
    int gid = blockIdx.x * 256 + threadIdx.x;     // 131072 threads
    int row = gid >> 2;                            // 0..32767 (b*N + n)
    int col = (gid & 3) * 16;
    float2 ml[4];
    float Mx = MASKV;
    #pragma unroll
    for (int s = 0; s < 4; ++s) {
        ml[s] = pml[s * (BATCH * NN) + row];
        Mx = fmaxf(Mx, ml[s].x);
    }
    float w[4], den = 0.f;
    #pragma unroll
    for (int s = 0; s < 4; ++s) {
        w[s] = __builtin_amdgcn_exp2f(ml[s].x - Mx);
        den += w[s] * ml[s].y;
    }
    float inv = 1.0f / den;                        // diag guarantees den > 0
    float acc[16] = {};
    #pragma unroll
    for (int s = 0; s < 4; ++s) {
        const _Float16* p = po + ((size_t)s * (BATCH * NN) + row) * 64 + col;
        float a = w[s] * inv;
        half8 v0 = *(const half8*)(p);
        half8 v1 = *(const half8*)(p + 8);
        #pragma unroll
        for (int j = 0; j < 8; ++j) {
            acc[j]     += a * (float)v0[j];
            acc[j + 8] += a * (float)v1[j];
        }
    }
    float* op = out + (size_t)row * 64 + col;
    #pragma unroll
    for (int i = 0; i < 4; ++i) {
        f32x4 r = {acc[4*i], acc[4*i+1], acc[4*i+2], acc[4*i+3]};
        *(f32x4*)(op + i*4) = r;
    }
}

extern "C" void kernel_launch(void* const* d_in, const int* in_sizes, int n_in,
                              void* d_out, int out_size, void* d_ws, size_t ws_size,
                              hipStream_t stream) {
    const float* X  = (const float*)d_in[0];
    const int*   A  = (const int*)d_in[1];
    const float* W0 = (const float*)d_in[2];
    const float* Wq = (const float*)d_in[3];
    const float* Wk = (const float*)d_in[4];
    float* out = (float*)d_out;
    char* ws = (char*)d_ws;
    const size_t SZ = (size_t)BATCH * NN * CC * 2;        // 4 MB per fp16 tensor
    _Float16* qh  = (_Float16*)(ws);
    _Float16* ql  = (_Float16*)(ws + SZ);
    _Float16* kbf = (_Float16*)(ws + 2*SZ);
    _Float16* vtb = (_Float16*)(ws + 3*SZ);
    char* Mbase = ws + 4*SZ;                               // 2 MB mask
    _Float16* po = (_Float16*)(Mbase + 2*1024*1024);       // 16 MB (4 splits fp16)
    float2* pml  = (float2*)(Mbase + 2*1024*1024 + 4*SZ);  // 1 MB

    hipLaunchKernelGGL(gat_proj, dim3(512),  dim3(256), 0, stream, X, W0, Wq, Wk, qh, ql, kbf, vtb);
    hipLaunchKernelGGL(gat_mask, dim3(4096), dim3(256), 0, stream, A, (unsigned short*)Mbase);
    hipLaunchKernelGGL(gat_attn, dim3(1024), dim3(256), 0, stream, qh, ql, kbf, vtb,
                       (const unsigned long long*)Mbase, po, pml);
    hipLaunchKernelGGL(gat_comb, dim3(512),  dim3(256), 0, stream, po, pml, out);
}

// Round 6
// 207.070 us; speedup vs baseline: 1.2539x; 1.2539x over previous
//
#include <hip/hip_runtime.h>
#include <stdint.h>

#define BATCH 8
#define NN 4096
#define CC 64
#define MASKV -1.0e30f
#define LOG2E 1.4426950408889634f

typedef _Float16 half8 __attribute__((ext_vector_type(8)));
typedef __fp16 fp16x2 __attribute__((ext_vector_type(2)));
typedef float f32x4 __attribute__((ext_vector_type(4)));

// ------------------------------------------------------------------
// Projection: q (fp16 hi+lo, pre-scaled by log2e), k (fp16), vT (fp16,
// [b][c][n]). Split-compensated fp16 MFMA -> only fp16 STORAGE
// rounding (2^-11) survives into the attention matmuls.
// ------------------------------------------------------------------
__global__ __launch_bounds__(256) void gat_proj(
    const float* __restrict__ X, const float* __restrict__ W0,
    const float* __restrict__ Wq, const float* __restrict__ Wk,
    _Float16* __restrict__ qh, _Float16* __restrict__ ql,
    _Float16* __restrict__ kb, _Float16* __restrict__ vt)
{
    __shared__ alignas(16) _Float16 WTh[3][64][72];   // [mat][c_out][c_in], +8 pad
    __shared__ alignas(16) _Float16 WTl[3][64][72];
    const int t = threadIdx.x;
    const float* Ws[3] = {W0, Wq, Wk};
    for (int e = t; e < 4096; e += 256) {
        int k = e >> 6, c = e & 63;
        #pragma unroll
        for (int m = 0; m < 3; ++m) {
            float w = Ws[m][e];
            _Float16 hi = (_Float16)w;
            WTh[m][c][k] = hi;
            WTl[m][c][k] = (_Float16)(w - (float)hi);
        }
    }
    __syncthreads();
    const int lane = t & 63, wv = t >> 6;
    const int cl = lane & 15, g = lane >> 4;
    {
        int tile = blockIdx.x * 4 + wv;               // 2048 tiles of 16 rows
        int gr = tile * 16;
        const float* xr = X + (size_t)(gr + cl) * CC;
        half8 xh[2], xl[2];
        #pragma unroll
        for (int kf = 0; kf < 2; ++kf) {
            f32x4 a0 = *(const f32x4*)(xr + g*8 + kf*32);
            f32x4 a1 = *(const f32x4*)(xr + g*8 + kf*32 + 4);
            half8 h, l;
            #pragma unroll
            for (int j = 0; j < 4; ++j) {
                _Float16 h0 = (_Float16)a0[j], h1 = (_Float16)a1[j];
                h[j]   = h0; l[j]   = (_Float16)(a0[j] - (float)h0);
                h[j+4] = h1; l[j+4] = (_Float16)(a1[j] - (float)h1);
            }
            xh[kf] = h; xl[kf] = l;
        }
        // q and k: D[row][c_out] = X * W
        #pragma unroll
        for (int mat = 1; mat <= 2; ++mat) {
            #pragma unroll
            for (int nt = 0; nt < 4; ++nt) {
                f32x4 acc = {0.f, 0.f, 0.f, 0.f};
                #pragma unroll
                for (int kf = 0; kf < 2; ++kf) {
                    half8 bh = *(const half8*)&WTh[mat][nt*16 + cl][g*8 + kf*32];
                    half8 bl = *(const half8*)&WTl[mat][nt*16 + cl][g*8 + kf*32];
                    acc = __builtin_amdgcn_mfma_f32_16x16x32_f16(xh[kf], bh, acc, 0, 0, 0);
                    acc = __builtin_amdgcn_mfma_f32_16x16x32_f16(xl[kf], bh, acc, 0, 0, 0);
                    acc = __builtin_amdgcn_mfma_f32_16x16x32_f16(xh[kf], bl, acc, 0, 0, 0);
                }
                #pragma unroll
                for (int i = 0; i < 4; ++i) {
                    size_t off = (size_t)(gr + 4*g + i) * CC + nt*16 + cl;
                    if (mat == 1) {
                        float qs = acc[i] * LOG2E;        // fold log2e for exp2 softmax
                        _Float16 hi = (_Float16)qs;
                        qh[off] = hi;
                        ql[off] = (_Float16)(qs - (float)hi);
                    } else {
                        kb[off] = (_Float16)acc[i];
                    }
                }
            }
        }
        // vT: D[c_out][row] = W^T * X^T -> [b][c][n] layout
        {
            int b = gr >> 12, n0 = gr & (NN - 1);
            #pragma unroll
            for (int mt = 0; mt < 4; ++mt) {
                f32x4 acc = {0.f, 0.f, 0.f, 0.f};
                #pragma unroll
                for (int kf = 0; kf < 2; ++kf) {
                    half8 ah = *(const half8*)&WTh[0][mt*16 + cl][g*8 + kf*32];
                    half8 al = *(const half8*)&WTl[0][mt*16 + cl][g*8 + kf*32];
                    acc = __builtin_amdgcn_mfma_f32_16x16x32_f16(ah, xh[kf], acc, 0, 0, 0);
                    acc = __builtin_amdgcn_mfma_f32_16x16x32_f16(al, xh[kf], acc, 0, 0, 0);
                    acc = __builtin_amdgcn_mfma_f32_16x16x32_f16(ah, xl[kf], acc, 0, 0, 0);
                }
                #pragma unroll
                for (int i = 0; i < 4; ++i) {
                    int co = mt*16 + 4*g + i;
                    vt[((size_t)b * CC + co) * NN + n0 + cl] = (_Float16)acc[i];
                }
            }
        }
    }
}

// ------------------------------------------------------------------
// Adjacency -> bitmask (forced diagonal). One block per row; each
// thread packs 16 keys (4x int4 loads) into one u16 store.
// ------------------------------------------------------------------
__global__ __launch_bounds__(256) void gat_mask(const int* __restrict__ A,
                                                unsigned short* __restrict__ M16)
{
    const int row = blockIdx.x;
    const int w16 = threadIdx.x;
    const int4* ap = (const int4*)(A + (size_t)row * NN + w16 * 16);
    unsigned m = 0;
    #pragma unroll
    for (int j = 0; j < 4; ++j) {
        int4 a = ap[j];
        m |= (a.x != 0 ? 1u : 0u) << (4*j);
        m |= (a.y != 0 ? 1u : 0u) << (4*j + 1);
        m |= (a.z != 0 ? 1u : 0u) << (4*j + 2);
        m |= (a.w != 0 ? 1u : 0u) << (4*j + 3);
    }
    if (w16 == (row >> 4)) m |= 1u << (row & 15);
    M16[(size_t)row * 256 + w16] = (unsigned short)m;
}

// ------------------------------------------------------------------
// Flash attention, split-K x4: 1024 blocks -> 4 blocks/CU (36 KB LDS,
// ~112 VGPR = 4 waves/SIMD naturally; NO min-waves clamp — round 5's
// __launch_bounds__(256,4) forced VGPR=64 and spilled ~300 MB to
// scratch). Block swizzle: b = blk & 7 so one batch's 128 blocks land
// on one XCD (round-robin dispatch) -> K/V stays in that XCD's L2.
// ------------------------------------------------------------------
__global__ __launch_bounds__(256) void gat_attn(
    const _Float16* __restrict__ qh, const _Float16* __restrict__ ql,
    const _Float16* __restrict__ kf16, const _Float16* __restrict__ vtb,
    const unsigned long long* __restrict__ M,
    _Float16* __restrict__ po, float2* __restrict__ pml)
{
    __shared__ alignas(16) _Float16 Kt[64][72];       // [key][c_in]
    __shared__ alignas(16) _Float16 Vt[64][72];       // [c_out][key]
    __shared__ alignas(16) _Float16 Ps[4][32][72];    // per-wave [qrow][key]
    const int t = threadIdx.x;
    const int lane = t & 63, wv = t >> 6;
    const int cl = lane & 15, g = lane >> 4;
    const int blk = blockIdx.x;        // 1024
    const int b  = blk & 7;            // batch == XCD (blk % 8 dispatch)
    const int sp = (blk >> 3) & 3;     // key split
    const int qb = blk >> 5;           // q tile 0..31
    const int Q0 = qb * 128 + wv * 32;
    const int c0 = sp * 16;            // first 64-key chunk of this split

    half8 qfh[2][2], qfl[2][2];
    #pragma unroll
    for (int qt = 0; qt < 2; ++qt) {
        const _Float16* qrh = qh + ((size_t)b * NN + Q0 + qt*16 + cl) * CC;
        const _Float16* qrl = ql + ((size_t)b * NN + Q0 + qt*16 + cl) * CC;
        qfh[qt][0] = *(const half8*)(qrh + g*8);
        qfh[qt][1] = *(const half8*)(qrh + g*8 + 32);
        qfl[qt][0] = *(const half8*)(qrl + g*8);
        qfl[qt][1] = *(const half8*)(qrl + g*8 + 32);
    }
    const _Float16* kg = kf16 + (size_t)b * NN * CC;
    const _Float16* vg = vtb + (size_t)b * CC * NN;

    f32x4 o[2][4] = {};
    float m_run[2] = {MASKV, MASKV}, l_run[2] = {0.f, 0.f};

    uint4 pk0, pk1, pv0, pv1;
    unsigned long long pmA, pmB;
    auto loadchunk = [&](int kc) {                    // kc = global chunk id
        const uint4* ks = (const uint4*)(kg + (size_t)kc * 64 * CC);
        pk0 = ks[t];
        pk1 = ks[t + 256];
        const _Float16* vs = vg + kc * 64;
        pv0 = *(const uint4*)(vs + (size_t)(t >> 3) * NN + (t & 7) * 8);
        pv1 = *(const uint4*)(vs + (size_t)((t >> 3) + 32) * NN + (t & 7) * 8);
        pmA = M[(size_t)(Q0 + cl) * 64 + kc];
        pmB = M[(size_t)(Q0 + 16 + cl) * 64 + kc];
    };
    loadchunk(c0);

    for (int kc = 0; kc < 16; ++kc) {
        __syncthreads();                 // previous tile's consumers done
        *(uint4*)&Kt[t >> 3][(t & 7) * 8] = pk0;
        *(uint4*)&Kt[(t >> 3) + 32][(t & 7) * 8] = pk1;
        *(uint4*)&Vt[t >> 3][(t & 7) * 8] = pv0;
        *(uint4*)&Vt[(t >> 3) + 32][(t & 7) * 8] = pv1;
        const unsigned long long cmA = pmA, cmB = pmB;
        __syncthreads();                 // tile ready
        if (kc < 15) loadchunk(c0 + kc + 1);   // overlap with compute

        // S^T tiles: D[key][qrow]; q hi/lo fp16 (K frag reused)
        f32x4 sc[2][4] = {};
        #pragma unroll
        for (int kt = 0; kt < 4; ++kt) {
            #pragma unroll
            for (int kf = 0; kf < 2; ++kf) {
                half8 ka = *(const half8*)&Kt[kt*16 + cl][g*8 + kf*32];
                sc[0][kt] = __builtin_amdgcn_mfma_f32_16x16x32_f16(ka, qfh[0][kf], sc[0][kt], 0, 0, 0);
                sc[0][kt] = __builtin_amdgcn_mfma_f32_16x16x32_f16(ka, qfl[0][kf], sc[0][kt], 0, 0, 0);
                sc[1][kt] = __builtin_amdgcn_mfma_f32_16x16x32_f16(ka, qfh[1][kf], sc[1][kt], 0, 0, 0);
                sc[1][kt] = __builtin_amdgcn_mfma_f32_16x16x32_f16(ka, qfl[1][kf], sc[1][kt], 0, 0, 0);
            }
        }

        // softmax (exp2 domain); lane owns q-row qt*16+cl
        #pragma unroll
        for (int qt = 0; qt < 2; ++qt) {
            const unsigned long long cm = qt ? cmB : cmA;
            const unsigned mwx = (unsigned)cm, mwy = (unsigned)(cm >> 32);
            float sv[16];
            float mx = MASKV;
            #pragma unroll
            for (int kt = 0; kt < 4; ++kt) {
                unsigned wmw = (kt < 2) ? mwx : mwy;
                #pragma unroll
                for (int i = 0; i < 4; ++i) {
                    float x = sc[qt][kt][i];
                    x = fmaxf(x, 0.01f * x);              // leaky_relu
                    int bit = ((kt & 1) * 16) + 4*g + i;
                    x = ((wmw >> bit) & 1u) ? x : MASKV;
                    sv[kt*4 + i] = x;
                    mx = fmaxf(mx, x);
                }
            }
            mx = fmaxf(mx, __shfl_xor(mx, 16));
            mx = fmaxf(mx, __shfl_xor(mx, 32));
            if (__any(mx > m_run[qt])) {                   // wave-uniform skip
                float nm = fmaxf(m_run[qt], mx);
                float alpha = __builtin_amdgcn_exp2f(m_run[qt] - nm);
                m_run[qt] = nm;
                l_run[qt] *= alpha;
                #pragma unroll
                for (int ct = 0; ct < 4; ++ct) o[qt][ct] *= alpha;
            }
            float lsum = 0.f;
            float p[16];
            #pragma unroll
            for (int j = 0; j < 16; ++j) {
                p[j] = __builtin_amdgcn_exp2f(sv[j] - m_run[qt]);  // masked -> 0
                lsum += p[j];
            }
            l_run[qt] += lsum;
            #pragma unroll
            for (int kt = 0; kt < 4; ++kt) {
                union { fp16x2 h; unsigned u; } p0u, p1u;
                p0u.h = __builtin_amdgcn_cvt_pkrtz(p[kt*4+0], p[kt*4+1]);
                p1u.h = __builtin_amdgcn_cvt_pkrtz(p[kt*4+2], p[kt*4+3]);
                uint2 pw = {p0u.u, p1u.u};
                *(uint2*)&Ps[wv][qt*16 + cl][kt*16 + 4*g] = pw;
            }
        }
        __builtin_amdgcn_wave_barrier();   // same-wave DS in-order; fence scheduler

        half8 pf[2][2];
        #pragma unroll
        for (int qt = 0; qt < 2; ++qt) {
            pf[qt][0] = *(const half8*)&Ps[wv][qt*16 + cl][g*8];
            pf[qt][1] = *(const half8*)&Ps[wv][qt*16 + cl][g*8 + 32];
        }
        // O^T += V^T * P^T
        #pragma unroll
        for (int ct = 0; ct < 4; ++ct) {
            half8 vf0 = *(const half8*)&Vt[ct*16 + cl][g*8];
            half8 vf1 = *(const half8*)&Vt[ct*16 + cl][g*8 + 32];
            #pragma unroll
            for (int qt = 0; qt < 2; ++qt) {
                o[qt][ct] = __builtin_amdgcn_mfma_f32_16x16x32_f16(vf0, pf[qt][0], o[qt][ct], 0, 0, 0);
                o[qt][ct] = __builtin_amdgcn_mfma_f32_16x16x32_f16(vf1, pf[qt][1], o[qt][ct], 0, 0, 0);
            }
        }
    }

    // epilogue: store UNNORMALIZED fp16 partial o + (m, l) for combine
    #pragma unroll
    for (int qt = 0; qt < 2; ++qt) {
        float lt = l_run[qt];
        lt += __shfl_xor(lt, 16);
        lt += __shfl_xor(lt, 32);
        size_t base = (size_t)sp * (BATCH * NN) + (size_t)b * NN + Q0 + qt*16 + cl;
        _Float16* orow = po + base * 64;
        #pragma unroll
        for (int ct = 0; ct < 4; ++ct) {
            union { fp16x2 h; unsigned u; } o0u, o1u;
            o0u.h = __builtin_amdgcn_cvt_pkrtz(o[qt][ct][0], o[qt][ct][1]);
            o1u.h = __builtin_amdgcn_cvt_pkrtz(o[qt][ct][2], o[qt][ct][3]);
            uint2 ow = {o0u.u, o1u.u};
            *(uint2*)(orow + ct*16 + 4*g) = ow;
        }
        if (g == 0) pml[base] = make_float2(m_run[qt], lt);
    }
}

// ------------------------------------------------------------------
// Combine the 4 split-K partials: out = sum_s w_s*o_s / sum_s w_s*l_s,
// w_s = exp2(m_s - max_s m_s). Fully-masked splits get w=0.
// ------------------------------------------------------------------
__global__ __launch_bounds__(256) void gat_comb(
    const _Float16* __restrict__ po, const float2* __restrict__ pml,
    float* __restrict__ out)
{
    int gid = blockIdx.x * 256 + threadIdx.x;     // 131072 threads
    int row = gid >> 2;                            // 0..32767 (b*N + n)
    int col = (gid & 3) * 16;
    float2 ml[4];
    float Mx = MASKV;
    #pragma unroll
    for (int s = 0; s < 4; ++s) {
        ml[s] = pml[s * (BATCH * NN) + row];
        Mx = fmaxf(Mx, ml[s].x);
    }
    float w[4], den = 0.f;
    #pragma unroll
    for (int s = 0; s < 4; ++s) {
        w[s] = __builtin_amdgcn_exp2f(ml[s].x - Mx);
        den += w[s] * ml[s].y;
    }
    float inv = 1.0f / den;                        // diag guarantees den > 0
    float acc[16] = {};
    #pragma unroll
    for (int s = 0; s < 4; ++s) {
        const _Float16* p = po + ((size_t)s * (BATCH * NN) + row) * 64 + col;
        float a = w[s] * inv;
        half8 v0 = *(const half8*)(p);
        half8 v1 = *(const half8*)(p + 8);
        #pragma unroll
        for (int j = 0; j < 8; ++j) {
            acc[j]     += a * (float)v0[j];
            acc[j + 8] += a * (float)v1[j];
        }
    }
    float* op = out + (size_t)row * 64 + col;
    #pragma unroll
    for (int i = 0; i < 4; ++i) {
        f32x4 r = {acc[4*i], acc[4*i+1], acc[4*i+2], acc[4*i+3]};
        *(f32x4*)(op + i*4) = r;
    }
}

extern "C" void kernel_launch(void* const* d_in, const int* in_sizes, int n_in,
                              void* d_out, int out_size, void* d_ws, size_t ws_size,
                              hipStream_t stream) {
    const float* X  = (const float*)d_in[0];
    const int*   A  = (const int*)d_in[1];
    const float* W0 = (const float*)d_in[2];
    const float* Wq = (const float*)d_in[3];
    const float* Wk = (const float*)d_in[4];
    float* out = (float*)d_out;
    char* ws = (char*)d_ws;
    const size_t SZ = (size_t)BATCH * NN * CC * 2;        // 4 MB per fp16 tensor
    _Float16* qh  = (_Float16*)(ws);
    _Float16* ql  = (_Float16*)(ws + SZ);
    _Float16* kbf = (_Float16*)(ws + 2*SZ);
    _Float16* vtb = (_Float16*)(ws + 3*SZ);
    char* Mbase = ws + 4*SZ;                               // 2 MB mask
    _Float16* po = (_Float16*)(Mbase + 2*1024*1024);       // 16 MB (4 splits fp16)
    float2* pml  = (float2*)(Mbase + 2*1024*1024 + 4*SZ);  // 1 MB

    hipLaunchKernelGGL(gat_proj, dim3(512),  dim3(256), 0, stream, X, W0, Wq, Wk, qh, ql, kbf, vtb);
    hipLaunchKernelGGL(gat_mask, dim3(4096), dim3(256), 0, stream, A, (unsigned short*)Mbase);
    hipLaunchKernelGGL(gat_attn, dim3(1024), dim3(256), 0, stream, qh, ql, kbf, vtb,
                       (const unsigned long long*)Mbase, po, pml);
    hipLaunchKernelGGL(gat_comb, dim3(512),  dim3(256), 0, stream, po, pml, out);
}